// Round 5
// baseline (3062.071 us; speedup 1.0000x reference)
//
#include <hip/hip_runtime.h>
#include <hip/hip_bf16.h>

// R-GCN 2-layer forward, fused per layer with edge-parallel LDS-atomic aggregation.
//   Sort key: (dst>>6)*576 + etype*64 + (dst&63); synthetic self-loop edges (etype=8).
//   fused_layer per 64-node block, r = 0..8:
//     edge-parallel: atomicAdd bf16 h[src] rows (fp32) into LDS At tile,
//     then MFMA K=128 chunk vs W_r, accumulate in regs across relations.

#define D 128

typedef __attribute__((ext_vector_type(8))) __bf16 bf16x8;
typedef __attribute__((ext_vector_type(8))) unsigned short us8;
typedef __attribute__((ext_vector_type(4))) unsigned short us4;
typedef __attribute__((ext_vector_type(4))) float f32x4;

__device__ __forceinline__ unsigned short f2bf(float f) {
    union { float f; unsigned u; } v; v.f = f;
    unsigned r = v.u + 0x7FFF + ((v.u >> 16) & 1);   // RNE
    return (unsigned short)(r >> 16);
}
__device__ __forceinline__ float bf2f(unsigned short u) {
    return __uint_as_float((unsigned)u << 16);
}

// Bt LDS swizzle (16B chunks): chunk' = c ^ (row&15)
__device__ __forceinline__ int eoff(int row, int c) {
    return row * 128 + ((c ^ (row & 15)) << 3);
}

// ---------------- sort: histogram / hierarchical scan / scatter ----------------
// e in [0,E): real edge.  e in [E,E+N): synthetic self-loop edge (etype=8, src=dst=e-E).

__global__ void hist_kernel(const int* __restrict__ src, const int* __restrict__ dst,
                            const int* __restrict__ et, int* __restrict__ cnt, int E, int N) {
    int e = blockIdx.x * blockDim.x + threadIdx.x;
    if (e < E + N) {
        int d, r;
        if (e < E) { d = dst[e]; r = et[e]; }
        else       { d = e - E;  r = 8; }
        atomicAdd(&cnt[(d >> 6) * 576 + r * 64 + (d & 63)], 1);
    }
}

__global__ __launch_bounds__(256) void scan_partial(const int* __restrict__ cnt,
                                                    int* __restrict__ part, int B) {
    int t = threadIdx.x;
    int base = blockIdx.x * 1024 + t * 4;
    int4 v = {0, 0, 0, 0};
    if (base + 3 < B) v = *(const int4*)(cnt + base);
    else {
        if (base     < B) v.x = cnt[base];
        if (base + 1 < B) v.y = cnt[base + 1];
        if (base + 2 < B) v.z = cnt[base + 2];
        if (base + 3 < B) v.w = cnt[base + 3];
    }
    int s = v.x + v.y + v.z + v.w;
    #pragma unroll
    for (int off = 32; off; off >>= 1) s += __shfl_down(s, off, 64);
    __shared__ int ws[4];
    int lane = t & 63, w = t >> 6;
    if (lane == 0) ws[w] = s;
    __syncthreads();
    if (t == 0) part[blockIdx.x] = ws[0] + ws[1] + ws[2] + ws[3];
}

__global__ __launch_bounds__(1024) void scan_root(int* __restrict__ part,
                                                  int* __restrict__ total, int NB) {
    int t = threadIdx.x;
    int v = (t < NB) ? part[t] : 0;
    int lane = t & 63, w = t >> 6;
    int inc = v;
    #pragma unroll
    for (int off = 1; off < 64; off <<= 1) {
        int n = __shfl_up(inc, off, 64);
        if (lane >= off) inc += n;
    }
    __shared__ int ws[16];
    if (lane == 63) ws[w] = inc;
    __syncthreads();
    int wbase = 0;
    for (int i = 0; i < w; ++i) wbase += ws[i];
    if (t < NB) part[t] = wbase + inc - v;
    if (t == NB - 1) *total = wbase + inc;
}

__global__ __launch_bounds__(256) void scan_final(const int* __restrict__ cnt,
                                                  const int* __restrict__ part,
                                                  int* __restrict__ offs,
                                                  int* __restrict__ head, int B) {
    int t = threadIdx.x;
    int base = blockIdx.x * 1024 + t * 4;
    int4 v = {0, 0, 0, 0};
    if (base + 3 < B) v = *(const int4*)(cnt + base);
    else {
        if (base     < B) v.x = cnt[base];
        if (base + 1 < B) v.y = cnt[base + 1];
        if (base + 2 < B) v.z = cnt[base + 2];
        if (base + 3 < B) v.w = cnt[base + 3];
    }
    int tsum = v.x + v.y + v.z + v.w;
    int lane = t & 63, w = t >> 6;
    int inc = tsum;
    #pragma unroll
    for (int off = 1; off < 64; off <<= 1) {
        int n = __shfl_up(inc, off, 64);
        if (lane >= off) inc += n;
    }
    __shared__ int ws[4];
    if (lane == 63) ws[w] = inc;
    __syncthreads();
    int wbase = 0;
    for (int i = 0; i < w; ++i) wbase += ws[i];
    int run = part[blockIdx.x] + wbase + inc - tsum;
    int4 o = {run, run + v.x, run + v.x + v.y, run + v.x + v.y + v.z};
    if (base + 3 < B) {
        *(int4*)(offs + base) = o;
        *(int4*)(head + base) = o;
    } else {
        if (base     < B) { offs[base]     = o.x; head[base]     = o.x; }
        if (base + 1 < B) { offs[base + 1] = o.y; head[base + 1] = o.y; }
        if (base + 2 < B) { offs[base + 2] = o.z; head[base + 2] = o.z; }
        if (base + 3 < B) { offs[base + 3] = o.w; head[base + 3] = o.w; }
    }
}

__global__ void scatter_kernel(const int* __restrict__ src, const int* __restrict__ dst,
                               const int* __restrict__ et, int* __restrict__ head,
                               int* __restrict__ sorted, int E, int N) {
    int e = blockIdx.x * blockDim.x + threadIdx.x;
    if (e < E + N) {
        int d, r, s;
        if (e < E) { d = dst[e]; r = et[e]; s = src[e]; }
        else       { d = e - E;  r = 8;     s = d; }
        int pos = atomicAdd(&head[(d >> 6) * 576 + r * 64 + (d & 63)], 1);
        sorted[pos] = ((d & 63) << 17) | s;     // node-in-block | src (src < 2^17)
    }
}

// ---------------- weight cast to r-major packed bf16: Bp[(r*128+o)*128 + i] ----------------

__global__ void castB_kernel(const float* __restrict__ W1, const float* __restrict__ lw1,
                             const float* __restrict__ W2, const float* __restrict__ lw2,
                             unsigned short* __restrict__ B1, unsigned short* __restrict__ B2) {
    int idx = blockIdx.x * blockDim.x + threadIdx.x;
    const int per = 1152 * 128;
    if (idx >= 2 * per) return;
    int layer = idx / per;
    int rem = idx - layer * per;
    int k = rem >> 7;        // r*128 + i
    int o = rem & 127;
    const float* W  = layer ? W2 : W1;
    const float* lw = layer ? lw2 : lw1;
    float val = (k < 1024) ? W[k * D + o] : lw[(k - 1024) * D + o];
    unsigned short* Bp = layer ? B2 : B1;
    int r = k >> 7, i = k & 127;
    Bp[((r * 128 + o) << 7) + i] = f2bf(val);
}

__global__ void castH_kernel(const float* __restrict__ h, unsigned short* __restrict__ hb, int n4) {
    int i = blockIdx.x * blockDim.x + threadIdx.x;
    if (i < n4) {
        float4 v = *(const float4*)(h + (size_t)i * 4);
        us4 o; o.x = f2bf(v.x); o.y = f2bf(v.y); o.z = f2bf(v.z); o.w = f2bf(v.w);
        *(us4*)(hb + (size_t)i * 4) = o;
    }
}

// ---------------- fused layer: edge-parallel LDS-atomic aggregate + MFMA ----------------
// At layout: row = node-in-block (stride 132 words), col c stored at pos (c&3)*32 + (c>>2).
// -> per-edge 4x ds_add_f32 hit all 32 banks 2-way (free); A-frag = 4x ds_read_b64.

__global__ __launch_bounds__(256, 2) void fused_layer(
        const unsigned short* __restrict__ hb,     // bf16 node features [N][128]
        const int* __restrict__ offs,              // bucket offsets [Nblk*576 + 1]
        const int* __restrict__ sorted,            // payloads, bucket-sorted
        const unsigned short* __restrict__ Bp,     // packed weights [9*128][128] bf16
        const float* __restrict__ bias,
        float* __restrict__ outf,                  // fp32 out (layer 2)
        unsigned short* __restrict__ outb,         // bf16 out (layer 1)
        int N, int relu_bf)
{
    __shared__ float At[9216];                 // 36 KB (64 rows x 132 words)
    __shared__ unsigned short Bt[16384];       // 32 KB  -> ~68 KB total, 2 blocks/CU

    const int t = threadIdx.x;
    const int lane = t & 63;
    const int w = t >> 6;            // wave 0..3
    const int half32 = (lane >> 5);  // which edge of the pair
    const int l32 = lane & 31;
    const int quad = lane >> 4;
    const int c16 = lane & 15;
    const int v0 = blockIdx.x * 64;
    const int base = blockIdx.x * 576;

    // prologue: zero At
    const f32x4 z4 = {0.f, 0.f, 0.f, 0.f};
    #pragma unroll
    for (int i = 0; i < 9; ++i) *(f32x4*)(At + t * 4 + i * 1024) = z4;

    f32x4 acc[8];
    #pragma unroll
    for (int j = 0; j < 8; ++j) acc[j] = z4;

    for (int r = 0; r < 9; ++r) {
        // stage W_r tile (prev MFMA reads finished at last barrier)
        {
            const unsigned short* bsrc = Bp + r * 16384;
            int row = t >> 1;
            int cb = (t & 1) * 8;
            #pragma unroll
            for (int j = 0; j < 8; ++j) {
                us8 vv = *(const us8*)(bsrc + (row << 7) + ((cb + j) << 3));
                *(us8*)(Bt + eoff(row, cb + j)) = vv;
            }
        }
        int e0 = offs[base + r * 64];
        int e1 = offs[base + r * 64 + 64];
        int per = ((e1 - e0) + 3) >> 2;
        int s = e0 + w * per;
        int tend = s + per; if (tend > e1) tend = e1; if (s > e1) s = e1;

        __syncthreads();   // B0: Bt staged, At zeroed

        #pragma unroll 4
        for (int e = s; e < tend; e += 2) {
            int i0 = e + half32;
            bool val = i0 < tend;
            int idx = sorted[val ? i0 : (tend - 1)];
            int nib = idx >> 17;
            int sc  = idx & 131071;
            us4 hv = *(const us4*)(hb + (size_t)sc * D + l32 * 4);
            float f0 = val ? bf2f(hv.x) : 0.f;
            float f1 = val ? bf2f(hv.y) : 0.f;
            float f2 = val ? bf2f(hv.z) : 0.f;
            float f3 = val ? bf2f(hv.w) : 0.f;
            float* An = At + nib * 132 + l32;
            atomicAdd(An,      f0);
            atomicAdd(An + 32, f1);
            atomicAdd(An + 64, f2);
            atomicAdd(An + 96, f3);
        }
        __syncthreads();   // B1: At complete

        // A-frags: rows w*16..w*16+15; lane row = w*16 + c16
        bf16x8 af[4];
        #pragma unroll
        for (int ks = 0; ks < 4; ++ks) {
            const float* arow = At + (w * 16 + c16) * 132 + ks * 8 + quad * 2;
            float2 q0 = *(const float2*)(arow);
            float2 q1 = *(const float2*)(arow + 32);
            float2 q2 = *(const float2*)(arow + 64);
            float2 q3 = *(const float2*)(arow + 96);
            us8 u;
            u[0] = f2bf(q0.x); u[1] = f2bf(q1.x); u[2] = f2bf(q2.x); u[3] = f2bf(q3.x);
            u[4] = f2bf(q0.y); u[5] = f2bf(q1.y); u[6] = f2bf(q2.y); u[7] = f2bf(q3.y);
            af[ks] = *(bf16x8*)&u;
        }
        #pragma unroll
        for (int ks = 0; ks < 4; ++ks) {
            int kc = ks * 4 + quad;
            #pragma unroll
            for (int ct = 0; ct < 8; ++ct) {
                bf16x8 bfr = *(const bf16x8*)(Bt + eoff(ct * 16 + c16, kc));
                acc[ct] = __builtin_amdgcn_mfma_f32_16x16x32_bf16(af[ks], bfr, acc[ct], 0, 0, 0);
            }
        }
        __syncthreads();   // B2: At/Bt reads done

        // re-zero At for next relation
        #pragma unroll
        for (int i = 0; i < 9; ++i) *(f32x4*)(At + t * 4 + i * 1024) = z4;
    }

    // epilogue: C[row=quad*4+i][col=c16] per 16x16 tile; wave strip rows w*16..+15
    int row0 = v0 + w * 16 + quad * 4;
    #pragma unroll
    for (int ct = 0; ct < 8; ++ct) {
        int col = ct * 16 + c16;
        float bcol = bias[col];
        #pragma unroll
        for (int i2 = 0; i2 < 4; ++i2) {
            int rr = row0 + i2;
            if (rr < N) {
                float vv = acc[ct][i2] + bcol;
                if (relu_bf) {
                    vv = fmaxf(vv, 0.f);
                    outb[(size_t)rr * D + col] = f2bf(vv);
                } else {
                    outf[(size_t)rr * D + col] = vv;
                }
            }
        }
    }
}

// ---------------- launch ----------------

extern "C" void kernel_launch(void* const* d_in, const int* in_sizes, int n_in,
                              void* d_out, int out_size, void* d_ws, size_t ws_size,
                              hipStream_t stream) {
    const float* feats = (const float*)d_in[0];
    const float* W1    = (const float*)d_in[1];
    const float* lw1   = (const float*)d_in[2];
    const float* b1    = (const float*)d_in[3];
    const float* W2    = (const float*)d_in[4];
    const float* lw2   = (const float*)d_in[5];
    const float* b2    = (const float*)d_in[6];
    const int*   src   = (const int*)d_in[7];
    const int*   dst   = (const int*)d_in[8];
    const int*   etype = (const int*)d_in[9];
    const int N = in_sizes[0] / D;
    const int E = in_sizes[7];
    const int Nblk = (N + 63) / 64;
    const int B = Nblk * 576;
    float* out = (float*)d_out;

    size_t woff = 0;
    auto take = [&](size_t bytes) -> void* {
        void* p = (char*)d_ws + woff;
        woff += (bytes + 255) & ~(size_t)255;
        return p;
    };
    int* cnt            = (int*)take((size_t)B * 4);
    int* offs           = (int*)take((size_t)(B + 1) * 4);
    int* head           = (int*)take((size_t)B * 4);
    int* part           = (int*)take((size_t)1024 * 4);
    int* sorted         = (int*)take((size_t)(E + N) * 4);
    unsigned short* Bp1 = (unsigned short*)take((size_t)1152 * 128 * 2);
    unsigned short* Bp2 = (unsigned short*)take((size_t)1152 * 128 * 2);
    unsigned short* hb0 = (unsigned short*)take((size_t)N * D * 2);
    unsigned short* hb1 = (unsigned short*)take((size_t)N * D * 2);

    (void)hipMemsetAsync(cnt, 0, (size_t)B * 4, stream);

    int eb = (E + N + 255) / 256;
    hist_kernel<<<eb, 256, 0, stream>>>(src, dst, etype, cnt, E, N);

    int NB = (B + 1023) / 1024;   // ~880 <= 1024
    scan_partial<<<NB, 256, 0, stream>>>(cnt, part, B);
    scan_root<<<1, 1024, 0, stream>>>(part, offs + B, NB);
    scan_final<<<NB, 256, 0, stream>>>(cnt, part, offs, head, B);

    scatter_kernel<<<eb, 256, 0, stream>>>(src, dst, etype, head, sorted, E, N);

    int cb = (2 * 1152 * 128 + 255) / 256;
    castB_kernel<<<cb, 256, 0, stream>>>(W1, lw1, W2, lw2, Bp1, Bp2);

    int n4 = N * D / 4;
    castH_kernel<<<(n4 + 255) / 256, 256, 0, stream>>>(feats, hb0, n4);

    // layer 1: hb0 -> hb1 (bf16, relu)
    fused_layer<<<Nblk, 256, 0, stream>>>(hb0, offs, sorted, Bp1, b1, out, hb1, N, 1);
    // layer 2: hb1 -> d_out (fp32)
    fused_layer<<<Nblk, 256, 0, stream>>>(hb1, offs, sorted, Bp2, b2, out, hb1, N, 0);
}

// Round 7
// 739.840 us; speedup vs baseline: 4.1388x; 4.1388x over previous
//
#include <hip/hip_runtime.h>
#include <hip/hip_bf16.h>

// R-GCN 2-layer forward, round-3 skeleton + bf16 feature table + chunked ACC:
//   counting-sort edges by dst; per node-chunk (2 chunks, ws fits 256MiB):
//   aggregate (node/half-wave, LDS wave-owned fp32 acc, zero atomics/conflicts)
//   -> bf16 ACC[chunk][1152] (slot 1024 = self-loop);
//   bf16 MFMA GEMM [chunk,1152]@[1152,128] + bias (+ReLU); layer-1 output
//   written directly as bf16 table for layer 2.

#define D 128
#define KTOT 1152
#define BK 32

typedef __attribute__((ext_vector_type(8))) __bf16 bf16x8;
typedef __attribute__((ext_vector_type(8))) unsigned short us8;
typedef __attribute__((ext_vector_type(4))) unsigned short us4;
typedef __attribute__((ext_vector_type(4))) float f32x4;

__device__ __forceinline__ unsigned short f2bf(float f) {
    union { float f; unsigned u; } v; v.f = f;
    unsigned r = v.u + 0x7FFF + ((v.u >> 16) & 1);   // RNE
    return (unsigned short)(r >> 16);
}
__device__ __forceinline__ float bf2f(unsigned short u) {
    return __uint_as_float((unsigned)u << 16);
}

__device__ __forceinline__ int lds_off(int row, int c) {
    return row * 32 + ((c ^ ((row >> 1) & 3)) << 3);
}

// ---------------- sort: histogram / hierarchical scan / scatter ----------------

__global__ void hist_kernel(const int* __restrict__ dst, int* __restrict__ cnt, int E) {
    int e = blockIdx.x * blockDim.x + threadIdx.x;
    if (e < E) atomicAdd(&cnt[dst[e]], 1);
}

__global__ __launch_bounds__(256) void scan_partial(const int* __restrict__ cnt,
                                                    int* __restrict__ part, int B) {
    int t = threadIdx.x;
    int base = blockIdx.x * 1024 + t * 4;
    int4 v = {0, 0, 0, 0};
    if (base + 3 < B) v = *(const int4*)(cnt + base);
    else {
        if (base     < B) v.x = cnt[base];
        if (base + 1 < B) v.y = cnt[base + 1];
        if (base + 2 < B) v.z = cnt[base + 2];
        if (base + 3 < B) v.w = cnt[base + 3];
    }
    int s = v.x + v.y + v.z + v.w;
    #pragma unroll
    for (int off = 32; off; off >>= 1) s += __shfl_down(s, off, 64);
    __shared__ int ws[4];
    int lane = t & 63, w = t >> 6;
    if (lane == 0) ws[w] = s;
    __syncthreads();
    if (t == 0) part[blockIdx.x] = ws[0] + ws[1] + ws[2] + ws[3];
}

__global__ __launch_bounds__(1024) void scan_root(int* __restrict__ part,
                                                  int* __restrict__ total, int NB) {
    int t = threadIdx.x;
    int v = (t < NB) ? part[t] : 0;
    int lane = t & 63, w = t >> 6;
    int inc = v;
    #pragma unroll
    for (int off = 1; off < 64; off <<= 1) {
        int n = __shfl_up(inc, off, 64);
        if (lane >= off) inc += n;
    }
    __shared__ int ws[16];
    if (lane == 63) ws[w] = inc;
    __syncthreads();
    int wbase = 0;
    for (int i = 0; i < w; ++i) wbase += ws[i];
    if (t < NB) part[t] = wbase + inc - v;
    if (t == NB - 1) *total = wbase + inc;
}

__global__ __launch_bounds__(256) void scan_final(const int* __restrict__ cnt,
                                                  const int* __restrict__ part,
                                                  int* __restrict__ offs,
                                                  int* __restrict__ head, int B) {
    int t = threadIdx.x;
    int base = blockIdx.x * 1024 + t * 4;
    int4 v = {0, 0, 0, 0};
    if (base + 3 < B) v = *(const int4*)(cnt + base);
    else {
        if (base     < B) v.x = cnt[base];
        if (base + 1 < B) v.y = cnt[base + 1];
        if (base + 2 < B) v.z = cnt[base + 2];
        if (base + 3 < B) v.w = cnt[base + 3];
    }
    int tsum = v.x + v.y + v.z + v.w;
    int lane = t & 63, w = t >> 6;
    int inc = tsum;
    #pragma unroll
    for (int off = 1; off < 64; off <<= 1) {
        int n = __shfl_up(inc, off, 64);
        if (lane >= off) inc += n;
    }
    __shared__ int ws[4];
    if (lane == 63) ws[w] = inc;
    __syncthreads();
    int wbase = 0;
    for (int i = 0; i < w; ++i) wbase += ws[i];
    int run = part[blockIdx.x] + wbase + inc - tsum;
    int4 o = {run, run + v.x, run + v.x + v.y, run + v.x + v.y + v.z};
    if (base + 3 < B) {
        *(int4*)(offs + base) = o;
        *(int4*)(head + base) = o;
    } else {
        if (base     < B) { offs[base]     = o.x; head[base]     = o.x; }
        if (base + 1 < B) { offs[base + 1] = o.y; head[base + 1] = o.y; }
        if (base + 2 < B) { offs[base + 2] = o.z; head[base + 2] = o.z; }
        if (base + 3 < B) { offs[base + 3] = o.w; head[base + 3] = o.w; }
    }
}

__global__ void scatter_kernel(const int* __restrict__ src, const int* __restrict__ dst,
                               const int* __restrict__ et, int* __restrict__ head,
                               int* __restrict__ sorted, int E) {
    int e = blockIdx.x * blockDim.x + threadIdx.x;
    if (e < E) {
        int pos = atomicAdd(&head[dst[e]], 1);
        sorted[pos] = (et[e] << 17) | src[e];   // src < 2^17
    }
}

// ---------------- combined cast: Bt[o][k] bf16 (both layers) + hb0 bf16 ----------------

__global__ void cast_kernel(const float* __restrict__ W1, const float* __restrict__ lw1,
                            const float* __restrict__ W2, const float* __restrict__ lw2,
                            const float* __restrict__ feats,
                            unsigned short* __restrict__ Bt1, unsigned short* __restrict__ Bt2,
                            unsigned short* __restrict__ hb0, int n4) {
    const int per = KTOT * D;          // 147456
    int idx = blockIdx.x * blockDim.x + threadIdx.x;
    if (idx < 2 * per) {
        int layer = idx / per;
        int rem = idx - layer * per;
        int k = rem >> 7;
        int o = rem & 127;             // coalesced read dim
        const float* W  = layer ? W2 : W1;
        const float* lw = layer ? lw2 : lw1;
        float val = (k < 1024) ? W[k * D + o] : lw[(k - 1024) * D + o];
        unsigned short* Bt = layer ? Bt2 : Bt1;
        Bt[o * KTOT + k] = f2bf(val);
    } else {
        int i = idx - 2 * per;
        if (i < n4) {
            float4 v = *(const float4*)(feats + (size_t)i * 4);
            us4 o; o.x = f2bf(v.x); o.y = f2bf(v.y); o.z = f2bf(v.z); o.w = f2bf(v.w);
            *(us4*)(hb0 + (size_t)i * 4) = o;
        }
    }
}

// ---------------- aggregation: node per half-wave, us4 = full row per instr ----------------

__global__ __launch_bounds__(256) void aggregate_kernel(const unsigned short* __restrict__ hb,
                                                        const int* __restrict__ offs,
                                                        const int* __restrict__ sorted,
                                                        unsigned short* __restrict__ A,
                                                        int v0, int vend) {
    const int t = threadIdx.x;
    const int wh = t >> 5;           // 0..7: half-wave unit, one node each
    const int l32 = t & 31;
    const int c = l32 * 4;           // 4 bf16 cols per lane
    const int v = v0 + blockIdx.x * 8 + wh;
    __shared__ float accs[8][1024];  // 32 KB; half-wave-owned region, no barriers/conflicts
    float* acc = accs[wh];
    const f32x4 z = {0.f, 0.f, 0.f, 0.f};
    #pragma unroll
    for (int r = 0; r < 8; ++r) *(f32x4*)(acc + r * 128 + c) = z;
    if (v >= vend) return;

    int e0 = offs[v], e1 = offs[v + 1];
    #pragma unroll 2
    for (int e = e0; e < e1; ++e) {
        int p = sorted[e];               // half-wave-uniform
        int s = p & 131071;
        int r = p >> 17;
        us4 hv = *(const us4*)(hb + (size_t)s * D + c);
        f32x4 a = *(f32x4*)(acc + r * 128 + c);
        a.x += bf2f(hv.x); a.y += bf2f(hv.y); a.z += bf2f(hv.z); a.w += bf2f(hv.w);
        *(f32x4*)(acc + r * 128 + c) = a;
    }

    size_t base = (size_t)(v - v0) * KTOT;
    #pragma unroll
    for (int r = 0; r < 8; ++r) {
        f32x4 a = *(f32x4*)(acc + r * 128 + c);
        us4 o; o.x = f2bf(a.x); o.y = f2bf(a.y); o.z = f2bf(a.z); o.w = f2bf(a.w);
        *(us4*)(A + base + r * 128 + c) = o;
    }
    us4 hv = *(const us4*)(hb + (size_t)v * D + c);   // self-loop: direct bf16 copy
    *(us4*)(A + base + 1024 + c) = hv;
}

// ---------------- GEMM: out[v0:vend][128] = ACC @ Bt^T + bias (+ReLU) ----------------

__global__ __launch_bounds__(256) void gemm_kernel(const unsigned short* __restrict__ A,
                                                   const unsigned short* __restrict__ Bt,
                                                   const float* __restrict__ bias,
                                                   float* __restrict__ outf,
                                                   unsigned short* __restrict__ outb,
                                                   int v0, int vend, int relu_bf) {
    __shared__ unsigned short Alds[128 * 32];
    __shared__ unsigned short Blds[128 * 32];
    const int t = threadIdx.x;
    const int lane = t & 63;
    const int w = t >> 6;
    const int quad = lane >> 4;
    const int c16 = lane & 15;
    const int blockRow0 = v0 + blockIdx.x * 128;

    const int srow = t >> 2;
    const int schunk = t & 3;

    f32x4 acc[2][8];
    #pragma unroll
    for (int i = 0; i < 2; ++i)
        #pragma unroll
        for (int j = 0; j < 8; ++j) acc[i][j] = f32x4{0.f, 0.f, 0.f, 0.f};

    const int aRow0 = blockRow0 + srow;
    const int aRow1 = blockRow0 + srow + 64;
    const bool val0 = aRow0 < vend;
    const bool val1 = aRow1 < vend;
    const us8 zz = {0, 0, 0, 0, 0, 0, 0, 0};

    for (int k0 = 0; k0 < KTOT; k0 += BK) {
        us8 av0 = zz, av1 = zz;
        if (val0) av0 = *(const us8*)(A + (size_t)(aRow0 - v0) * KTOT + k0 + schunk * 8);
        if (val1) av1 = *(const us8*)(A + (size_t)(aRow1 - v0) * KTOT + k0 + schunk * 8);
        us8 bv0 = *(const us8*)(Bt + (size_t)srow * KTOT + k0 + schunk * 8);
        us8 bv1 = *(const us8*)(Bt + (size_t)(srow + 64) * KTOT + k0 + schunk * 8);
        __syncthreads();
        *(us8*)(Alds + lds_off(srow,      schunk)) = av0;
        *(us8*)(Alds + lds_off(srow + 64, schunk)) = av1;
        *(us8*)(Blds + lds_off(srow,      schunk)) = bv0;
        *(us8*)(Blds + lds_off(srow + 64, schunk)) = bv1;
        __syncthreads();

        bf16x8 af[2];
        #pragma unroll
        for (int rt = 0; rt < 2; ++rt)
            af[rt] = *(const bf16x8*)(Alds + lds_off(w * 32 + rt * 16 + c16, quad));
        #pragma unroll
        for (int ct = 0; ct < 8; ++ct) {
            bf16x8 bfr = *(const bf16x8*)(Blds + lds_off(ct * 16 + c16, quad));
            acc[0][ct] = __builtin_amdgcn_mfma_f32_16x16x32_bf16(af[0], bfr, acc[0][ct], 0, 0, 0);
            acc[1][ct] = __builtin_amdgcn_mfma_f32_16x16x32_bf16(af[1], bfr, acc[1][ct], 0, 0, 0);
        }
    }

    // epilogue: C[row=quad*4+i][col=c16] per 16x16 tile (verified r3)
    #pragma unroll
    for (int rt = 0; rt < 2; ++rt) {
        int row = blockRow0 + w * 32 + rt * 16 + quad * 4;
        #pragma unroll
        for (int ct = 0; ct < 8; ++ct) {
            int col = ct * 16 + c16;
            float bcol = bias[col];
            #pragma unroll
            for (int i = 0; i < 4; ++i) {
                int r = row + i;
                if (r < vend) {
                    float vv = acc[rt][ct][i] + bcol;
                    if (relu_bf) {
                        vv = fmaxf(vv, 0.f);
                        outb[(size_t)r * D + col] = f2bf(vv);
                    } else {
                        outf[(size_t)r * D + col] = vv;
                    }
                }
            }
        }
    }
}

// ---------------- launch ----------------

extern "C" void kernel_launch(void* const* d_in, const int* in_sizes, int n_in,
                              void* d_out, int out_size, void* d_ws, size_t ws_size,
                              hipStream_t stream) {
    const float* feats = (const float*)d_in[0];
    const float* W1    = (const float*)d_in[1];
    const float* lw1   = (const float*)d_in[2];
    const float* b1    = (const float*)d_in[3];
    const float* W2    = (const float*)d_in[4];
    const float* lw2   = (const float*)d_in[5];
    const float* b2    = (const float*)d_in[6];
    const int*   src   = (const int*)d_in[7];
    const int*   dst   = (const int*)d_in[8];
    const int*   etype = (const int*)d_in[9];
    const int N = in_sizes[0] / D;
    const int E = in_sizes[7];
    float* out = (float*)d_out;

    const int ch = (N + 1) / 2;    // node chunk size (2 chunks keep ws < 256 MiB)

    size_t woff = 0;
    auto take = [&](size_t bytes) -> void* {
        void* p = (char*)d_ws + woff;
        woff += (bytes + 255) & ~(size_t)255;
        return p;
    };
    int* cnt            = (int*)take((size_t)N * 4);
    int* offs           = (int*)take((size_t)(N + 1) * 4);
    int* head           = (int*)take((size_t)N * 4);
    int* part           = (int*)take((size_t)1024 * 4);
    int* sorted         = (int*)take((size_t)E * 4);
    unsigned short* Bt1 = (unsigned short*)take((size_t)KTOT * D * 2);
    unsigned short* Bt2 = (unsigned short*)take((size_t)KTOT * D * 2);
    unsigned short* hb0 = (unsigned short*)take((size_t)N * D * 2);
    unsigned short* hb1 = (unsigned short*)take((size_t)N * D * 2);
    unsigned short* ACC = (unsigned short*)take((size_t)ch * KTOT * 2);   // ~115 MB

    (void)hipMemsetAsync(cnt, 0, (size_t)N * 4, stream);

    int eb = (E + 255) / 256;
    hist_kernel<<<eb, 256, 0, stream>>>(dst, cnt, E);

    int NB = (N + 1023) / 1024;
    scan_partial<<<NB, 256, 0, stream>>>(cnt, part, N);
    scan_root<<<1, 1024, 0, stream>>>(part, offs + N, NB);
    scan_final<<<NB, 256, 0, stream>>>(cnt, part, offs, head, N);

    scatter_kernel<<<eb, 256, 0, stream>>>(src, dst, etype, head, sorted, E);

    int n4 = N * D / 4;
    int cb = (2 * KTOT * D + n4 + 255) / 256;
    cast_kernel<<<cb, 256, 0, stream>>>(W1, lw1, W2, lw2, feats, Bt1, Bt2, hb0, n4);

    for (int layer = 0; layer < 2; ++layer) {
        const unsigned short* hin = layer ? hb1 : hb0;
        const unsigned short* Bt  = layer ? Bt2 : Bt1;
        const float* bias         = layer ? b2  : b1;
        for (int c0 = 0; c0 < N; c0 += ch) {
            int c1 = (c0 + ch < N) ? (c0 + ch) : N;
            int len = c1 - c0;
            int ab = (len + 7) / 8;
            int gb = (len + 127) / 128;
            aggregate_kernel<<<ab, 256, 0, stream>>>(hin, offs, sorted, ACC, c0, c1);
            gemm_kernel<<<gb, 256, 0, stream>>>(ACC, Bt, bias, out, hb1, c0, c1, 1 - layer);
        }
    }
}